// Round 8
// baseline (185.483 us; speedup 1.0000x reference)
//
#include <hip/hip_runtime.h>
#include <hip/hip_fp8.h>
#include <cstdint>

// ---------------------------------------------------------------------------
// DeepFM forward, MI355X (R8).
//   Stage 1: prep — W1..W3 f32->fp4 W^T (pre-scaled 2^7)  +  gather: embed_x
//            fp8 (B,512), per-sample lin, FM partials    [one fused kernel]
//   Stage 2: reduce — batch-global FM scalar S (fp32, reference quirk)
//   Stage 3: 3x mixed MFMA GEMM: A=fp8 acts, B=fp4 weights (16x16x128
//            f8f6f4, cbsz=0/blgp=4), bias+ReLU, fp8 out — REGISTER-PREFETCH
//            pipelined K-loop (R8 change)
//   Stage 4: L4 dot (512->1, fp32 weights) + sigmoid(fm + mlp)
//
// R8 change vs R7: GEMM staging switched from global_load_lds (whose
// barrier-forced s_waitcnt vmcnt(0) exposed full load latency BEFORE compute
// -> MfmaUtil 6.8%) to a global->VGPR->LDS pipeline: ds_write tile k, barrier
// (vmcnt-free), issue global loads tile k+1, MFMA tile k (hides latency),
// barrier (drain lands after compute). LDS layout/swizzles byte-identical to
// R7's verified scheme. __launch_bounds__(256,2) caps VGPRs at 256.
// Harness note: ~55-60 us of graph time is harness d_ws poison + d_in
// restore (268 MB fill @6.3 TB/s) — not addressable from kernel code.
// ---------------------------------------------------------------------------

typedef float f32x4 __attribute__((ext_vector_type(4)));
typedef int i32x4 __attribute__((ext_vector_type(4)));
typedef int i32x8 __attribute__((ext_vector_type(8)));

// fp4 e2m1 encode (weights only; RNE; magnitudes 0,.5,1,1.5,2,3,4,6)
__device__ inline uint32_t f2fp4(float v) {
  uint32_t s = (__float_as_uint(v) >> 31) << 3;
  float a = fabsf(v);
  uint32_t m;
  if (a < 0.25f) m = 0;
  else if (a < 0.75f) m = 1;
  else if (a < 1.25f) m = 2;
  else if (a < 1.75f) m = 3;
  else if (a < 2.5f)  m = 4;
  else if (a < 3.5f)  m = 5;
  else if (a < 5.0f)  m = 6;
  else m = 7;
  return s | m;
}
__device__ inline float fp82f(uint8_t b) {
  __hip_fp8_e4m3 t;
  t.__x = b;
  return (float)t;
}

// ---------------- workspace layout (bytes) ---------------------------------
static constexpr size_t OFF_LIN  = 0;                          // 16384 f32
static constexpr size_t OFF_PART = 65536;                      // 4096 f32
static constexpr size_t OFF_S    = 81920;                      // 1 f32
static constexpr size_t OFF_EMB  = 131072;                     // B*512 fp8
static constexpr size_t OFF_H1   = OFF_EMB + 8388608ull;       // B*2048 fp8
static constexpr size_t OFF_H2   = OFF_H1 + 33554432ull;       // B*1024 fp8
static constexpr size_t OFF_H3   = OFF_H2 + 16777216ull;       // B*512 fp8
static constexpr size_t OFF_W1T  = OFF_H3 + 8388608ull;        // 2048*512 fp4
static constexpr size_t OFF_W2T  = OFF_W1T + 524288ull;        // 1024*2048 fp4
static constexpr size_t OFF_W3T  = OFF_W2T + 1048576ull;       // 512*1024 fp4

// ---------------- Stage 1: fused prep (transposes + gather) ----------------
__global__ void prep(const float* __restrict__ W1, const float* __restrict__ W2,
                     const float* __restrict__ W3, uint8_t* __restrict__ W1T,
                     uint8_t* __restrict__ W2T, uint8_t* __restrict__ W3T,
                     const float* __restrict__ x, const float* __restrict__ fc,
                     const float* __restrict__ emb, uint8_t* __restrict__ ebf,
                     float* __restrict__ lin, float* __restrict__ partials) {
  __shared__ __align__(16) float smem[32 * 33];
  int blk = blockIdx.x;
  int tid = threadIdx.x;
  if (blk < 3584) {  // ---- transpose ----
    const float* W;
    uint8_t* WT;
    int K, N, bx, by;
    if (blk < 1024) {        // W1: K=512, N=2048
      W = W1; WT = W1T; K = 512; N = 2048; bx = blk & 63; by = blk >> 6;
    } else if (blk < 3072) { // W2: K=2048, N=1024
      int t = blk - 1024;
      W = W2; WT = W2T; K = 2048; N = 1024; bx = t & 31; by = t >> 5;
    } else {                 // W3: K=1024, N=512
      int t = blk - 3072;
      W = W3; WT = W3T; K = 1024; N = 512; bx = t & 15; by = t >> 4;
    }
    int tx = tid & 31, ty = tid >> 5;
    int n0 = bx * 32, k0 = by * 32;
#pragma unroll
    for (int i = ty; i < 32; i += 8)
      smem[i * 33 + tx] = W[(size_t)(k0 + i) * N + n0 + tx];
    __syncthreads();
    if (tx < 16) {
#pragma unroll
      for (int i = ty; i < 32; i += 8) {
        uint32_t lo = f2fp4(smem[(2 * tx) * 33 + i] * 128.f);
        uint32_t hi = f2fp4(smem[(2 * tx + 1) * 33 + i] * 128.f);
        WT[(size_t)(n0 + i) * (K >> 1) + (k0 >> 1) + tx] =
            (uint8_t)(lo | (hi << 4));
      }
    }
  } else {  // ---- gather ----
    int gb = blk - 3584;
    int wv = tid >> 6, lane = tid & 63;
    int b = gb * 4 + wv;
    int f = lane >> 4;
    int idx = (int)x[b * 4 + f];               // raw index (NO offset) for emb
    const float* row = emb + (size_t)idx * 128 + (lane & 15) * 8;
    float4 v0 = ((const float4*)row)[0];
    float4 v1 = ((const float4*)row)[1];
    float s = v0.x + v0.y + v0.z + v0.w + v1.x + v1.y + v1.z + v1.w;
    float q = v0.x * v0.x + v0.y * v0.y + v0.z * v0.z + v0.w * v0.w +
              v1.x * v1.x + v1.y * v1.y + v1.z * v1.z + v1.w * v1.w;

    int lo = 0, hi = 0;
    lo = __builtin_amdgcn_cvt_pk_fp8_f32(v0.x, v0.y, lo, false);
    lo = __builtin_amdgcn_cvt_pk_fp8_f32(v0.z, v0.w, lo, true);
    hi = __builtin_amdgcn_cvt_pk_fp8_f32(v1.x, v1.y, hi, false);
    hi = __builtin_amdgcn_cvt_pk_fp8_f32(v1.z, v1.w, hi, true);
    int2 pk = make_int2(lo, hi);
    *(int2*)(ebf + (size_t)b * 512 + lane * 8) = pk;   // 8 B/lane coalesced

    float lp = 0.f;
    if ((lane & 15) == 0) {                    // fc lookup USES offsets
      int off = (f == 1) ? 31360 : (f == 2) ? 38167 : (f == 3) ? 38185 : 0;
      lp = fc[idx + off];
    }
#pragma unroll
    for (int m = 32; m; m >>= 1) {
      s += __shfl_xor(s, m);
      q += __shfl_xor(q, m);
      lp += __shfl_xor(lp, m);
    }
    float* pt = smem;
    if (lane == 0) {
      lin[b] = lp;
      pt[wv] = s * s - q;                      // per-sample FM term
    }
    __syncthreads();
    if (tid == 0) partials[gb] = pt[0] + pt[1] + pt[2] + pt[3];
  }
}

// ---------------- Stage 2: reduce FM partials -> scalar S ------------------
__global__ void reduce_partials(const float* __restrict__ p,
                                float* __restrict__ S) {
  int tid = threadIdx.x;
  float v = 0.f;
  for (int i = tid; i < 4096; i += 256) v += p[i];
#pragma unroll
  for (int m = 32; m; m >>= 1) v += __shfl_xor(v, m);
  __shared__ float ps[4];
  if ((tid & 63) == 0) ps[tid >> 6] = v;
  __syncthreads();
  if (tid == 0) S[0] = ps[0] + ps[1] + ps[2] + ps[3];
}

// ---------------- Stage 3: mixed GEMM, C = relu(A*B + bias) ----------------
// A fp8 (stride K B), BT fp4 (stride K/2 B), C fp8 (stride N B).
// 128x128 tile, BK=256 elems, 4 waves of 64x64. Register-prefetch pipeline:
//   prologue: global->reg tile0
//   iter k: ds_write tile k; barrier (vmcnt-free); global->reg tile k+1;
//           MFMA tile k (hides load latency); barrier (drain post-compute).
// LDS layout identical to R7 (A rows 256 B, 16-chunk XOR swizzle; B rows
// 128 B, 8-chunk XOR swizzle — measured conflict-free).
// MFMA 16x16x128 f8f6f4: cbsz=0 (fp8 A), blgp=4 (fp4 B),
// scale_a=1 (0x7F), scale_b=2^-7 (0x78, undoes W pre-scale).
// 1-D grid, XCD swizzle: same-A-strip blocks share bid%8. GX = N/128.
__global__ __launch_bounds__(256, 2) void gemm_mx_relu(
    const uint8_t* __restrict__ A, const uint8_t* __restrict__ BT,
    const float* __restrict__ bias, uint8_t* __restrict__ C, int K, int N,
    int GX) {
  __shared__ __align__(16) uint8_t As[128][256];   // 32 KB
  __shared__ __align__(16) uint8_t Bs[128][128];   // 16 KB
  int bid = blockIdx.x;
  int by = (bid & 7) + ((bid >> 3) / GX) * 8;
  int bx = (bid >> 3) & (GX - 1);
  int tid = threadIdx.x;
  int wv = tid >> 6, lane = tid & 63;
  int m0 = by * 128, n0 = bx * 128;
  int mw = (wv >> 1) * 64, nw = (wv & 1) * 64;
  int ml = lane & 15, kg = lane >> 4;
  int Kb2 = K >> 1;
  // A staging map (same bytes as R7's global_load_lds scheme):
  //   lane covers row 16r+4wv+arow, LDS col al*16, global chunk al^(row&15)
  int al = lane & 15, arow = lane >> 4;
  int acol = (al ^ (4 * wv + arow)) * 16;
  // B staging map: row 32r+8wv+brow, LDS col bl*16, global chunk bl^brow
  int bl = lane & 7, brow = lane >> 3;
  int bcol = (bl ^ brow) * 16;

  f32x4 acc[4][4];
#pragma unroll
  for (int i = 0; i < 4; ++i)
#pragma unroll
    for (int j = 0; j < 4; ++j) acc[i][j] = (f32x4){0.f, 0.f, 0.f, 0.f};

  i32x4 pa[8], pb[4];
  // prologue: prefetch tile 0 into registers
#pragma unroll
  for (int r = 0; r < 8; ++r)
    pa[r] = *(const i32x4*)(A + (size_t)(m0 + 16 * r + 4 * wv + arow) * K +
                            acol);
#pragma unroll
  for (int r = 0; r < 4; ++r)
    pb[r] = *(const i32x4*)(BT + (size_t)(n0 + 32 * r + 8 * wv + brow) * Kb2 +
                            bcol);

  for (int kt = 0; kt < K; kt += 256) {
    // commit prefetched tile k to LDS
#pragma unroll
    for (int r = 0; r < 8; ++r)
      *(i32x4*)&As[16 * r + 4 * wv + arow][al * 16] = pa[r];
#pragma unroll
    for (int r = 0; r < 4; ++r)
      *(i32x4*)&Bs[32 * r + 8 * wv + brow][bl * 16] = pb[r];
    __syncthreads();   // vmcnt-free: no globals in flight here

    // issue prefetch for tile k+1 (consumed next iteration, after MFMAs)
    if (kt + 256 < K) {
#pragma unroll
      for (int r = 0; r < 8; ++r)
        pa[r] = *(const i32x4*)(A +
                                (size_t)(m0 + 16 * r + 4 * wv + arow) * K +
                                kt + 256 + acol);
#pragma unroll
      for (int r = 0; r < 4; ++r)
        pb[r] = *(const i32x4*)(BT +
                                (size_t)(n0 + 32 * r + 8 * wv + brow) * Kb2 +
                                ((kt + 256) >> 1) + bcol);
    }

    // compute tile k from LDS
    i32x4 z = (i32x4){0, 0, 0, 0};
#pragma unroll
    for (int j = 0; j < 2; ++j) {              // two 128-elem k-halves
      int c0 = 8 * j + 2 * kg;                 // A chunks (of 16)
      int pa0 = (c0 ^ ml) * 16;
      int pa1 = ((c0 + 1) ^ ml) * 16;
      int pbo = ((4 * j + kg) ^ (ml & 7)) * 16;  // B chunk (of 8)
      i32x8 af[4], bfr[4];
#pragma unroll
      for (int t = 0; t < 4; ++t) {
        int ra = mw + t * 16 + ml;
        i32x4 a0 = *(const i32x4*)&As[ra][pa0];
        i32x4 a1 = *(const i32x4*)&As[ra][pa1];
        af[t] = __builtin_shufflevector(a0, a1, 0, 1, 2, 3, 4, 5, 6, 7);
        i32x4 vb = *(const i32x4*)&Bs[nw + t * 16 + ml][pbo];
        bfr[t] = __builtin_shufflevector(vb, z, 0, 1, 2, 3, 4, 5, 6, 7);
      }
#pragma unroll
      for (int mt = 0; mt < 4; ++mt)
#pragma unroll
        for (int nt = 0; nt < 4; ++nt)
          acc[mt][nt] = __builtin_amdgcn_mfma_scale_f32_16x16x128_f8f6f4(
              af[mt], bfr[nt], acc[mt][nt],
              /*cbsz=fp8*/ 0, /*blgp=fp4*/ 4,
              0, 0x7F7F7F7F,      // scale_a = 1.0
              0, 0x78787878);     // scale_b = 2^-7
    }
    __syncthreads();   // prefetch loads have had the MFMA block to complete
  }

  // Epilogue: C/D layout col=lane&15, row=(lane>>4)*4+reg.
  // HW packed fp8 convert, byte stores.
  int rbase = kg * 4;
#pragma unroll
  for (int nt = 0; nt < 4; ++nt) {
    int col = n0 + nw + nt * 16 + ml;
    float bv = bias[col];
#pragma unroll
    for (int mt = 0; mt < 4; ++mt) {
      int row = m0 + mw + mt * 16 + rbase;
      float v0 = acc[mt][nt][0] + bv, v1 = acc[mt][nt][1] + bv;
      float v2 = acc[mt][nt][2] + bv, v3 = acc[mt][nt][3] + bv;
      v0 = v0 > 0.f ? v0 : 0.f;
      v1 = v1 > 0.f ? v1 : 0.f;
      v2 = v2 > 0.f ? v2 : 0.f;
      v3 = v3 > 0.f ? v3 : 0.f;
      int w01 = __builtin_amdgcn_cvt_pk_fp8_f32(v0, v1, 0, false);
      int w23 = __builtin_amdgcn_cvt_pk_fp8_f32(v2, v3, 0, false);
      C[(size_t)(row + 0) * N + col] = (uint8_t)(w01 & 0xFF);
      C[(size_t)(row + 1) * N + col] = (uint8_t)((w01 >> 8) & 0xFF);
      C[(size_t)(row + 2) * N + col] = (uint8_t)(w23 & 0xFF);
      C[(size_t)(row + 3) * N + col] = (uint8_t)((w23 >> 8) & 0xFF);
    }
  }
}

// ---------------- Stage 4: L4 (512->1) + sigmoid ---------------------------
__global__ void mlp_out_sigmoid(const uint8_t* __restrict__ h3,
                                const float* __restrict__ W4,
                                const float* __restrict__ b4,
                                const float* __restrict__ bias,
                                const float* __restrict__ lin,
                                const float* __restrict__ S,
                                float* __restrict__ out) {
  int tid = threadIdx.x;
  int wv = tid >> 6, lane = tid & 63;
  int b = blockIdx.x * 4 + wv;
  uint64_t pk = *(const uint64_t*)(h3 + (size_t)b * 512 + lane * 8);
  const float* wp = W4 + lane * 8;
  float4 w0 = ((const float4*)wp)[0];
  float4 w1 = ((const float4*)wp)[1];
  float wf[8] = {w0.x, w0.y, w0.z, w0.w, w1.x, w1.y, w1.z, w1.w};
  float acc = 0.f;
#pragma unroll
  for (int j = 0; j < 8; ++j)
    acc += fp82f((uint8_t)(pk >> (8 * j))) * wf[j];
#pragma unroll
  for (int m = 32; m; m >>= 1) acc += __shfl_xor(acc, m);
  if (lane == 0) {
    float z = acc + b4[0] + bias[0] + lin[b] + 0.5f * S[0];
    out[b] = 1.f / (1.f + expf(-z));
  }
}

// ---------------------------------------------------------------------------
extern "C" void kernel_launch(void* const* d_in, const int* in_sizes, int n_in,
                              void* d_out, int out_size, void* d_ws,
                              size_t ws_size, hipStream_t stream) {
  const float* x    = (const float*)d_in[0];
  const float* bias = (const float*)d_in[1];
  const float* fc   = (const float*)d_in[2];
  const float* emb  = (const float*)d_in[3];
  const float* W1   = (const float*)d_in[4];
  const float* b1   = (const float*)d_in[5];
  const float* W2   = (const float*)d_in[6];
  const float* b2   = (const float*)d_in[7];
  const float* W3   = (const float*)d_in[8];
  const float* b3   = (const float*)d_in[9];
  const float* W4   = (const float*)d_in[10];
  const float* b4   = (const float*)d_in[11];
  float* out = (float*)d_out;

  char* ws = (char*)d_ws;
  float* lin    = (float*)(ws + OFF_LIN);
  float* part   = (float*)(ws + OFF_PART);
  float* Sp     = (float*)(ws + OFF_S);
  uint8_t* EMBb = (uint8_t*)(ws + OFF_EMB);
  uint8_t* H1   = (uint8_t*)(ws + OFF_H1);
  uint8_t* H2   = (uint8_t*)(ws + OFF_H2);
  uint8_t* H3   = (uint8_t*)(ws + OFF_H3);
  uint8_t* W1T  = (uint8_t*)(ws + OFF_W1T);
  uint8_t* W2T  = (uint8_t*)(ws + OFF_W2T);
  uint8_t* W3T  = (uint8_t*)(ws + OFF_W3T);

  prep<<<7680, 256, 0, stream>>>(W1, W2, W3, W1T, W2T, W3T, x, fc, emb, EMBb,
                                 lin, part);
  reduce_partials<<<1, 256, 0, stream>>>(part, Sp);

  gemm_mx_relu<<<2048, 256, 0, stream>>>(EMBb, W1T, b1, H1, 512, 2048, 16);
  gemm_mx_relu<<<1024, 256, 0, stream>>>(H1, W2T, b2, H2, 2048, 1024, 8);
  gemm_mx_relu<<<512, 256, 0, stream>>>(H2, W3T, b3, H3, 1024, 512, 4);

  mlp_out_sigmoid<<<4096, 256, 0, stream>>>(H3, W4, b4, bias, lin, Sp, out);
}

// Round 9
// 174.822 us; speedup vs baseline: 1.0610x; 1.0610x over previous
//
#include <hip/hip_runtime.h>
#include <hip/hip_fp8.h>
#include <cstdint>

// ---------------------------------------------------------------------------
// DeepFM forward, MI355X (R9).
//   Stage 1: prep — W1..W3 f32->fp4 W^T (pre-scaled 2^7)  +  gather: embed_x
//            fp8 (B,512), per-sample lin, FM partials    [one fused kernel]
//   Stage 2: reduce — batch-global FM scalar S (fp32) + zero mlp accumulator
//   Stage 3: GEMM1, GEMM2 (A=fp8 acts, B=fp4 weights, 16x16x128 f8f6f4,
//            cbsz=0/blgp=4, global_load_lds staging), bias+ReLU, fp8 out
//   Stage 4: GEMM3 with FUSED L4: epilogue dots relu(H2*W3+b3) slice with W4
//            in-register, atomicAdd per-sample partials (H3 never exists)
//   Stage 5: final — sigmoid(fm + mlp) over 16384 samples
//
// R9 vs R8: reverted register-prefetch pipeline (R8 neutral-negative: +48
// VGPRs crossed the 3-blocks/CU boundary, occupancy loss ate the latency
// gain). Fused mlp_out into GEMM3 epilogue (eliminates H3: 16.8 MB traffic
// + one kernel). Budget note: ~100 us of dur_us is harness reset (268 MB
// 0xAA ws-poison + ~13 reset nodes); our kernels ~81 us.
// ---------------------------------------------------------------------------

typedef float f32x4 __attribute__((ext_vector_type(4)));
typedef int i32x4 __attribute__((ext_vector_type(4)));
typedef int i32x8 __attribute__((ext_vector_type(8)));

#define GLOAD16(gptr, lptr)                                                \
  __builtin_amdgcn_global_load_lds(                                        \
      (const __attribute__((address_space(1))) void*)(gptr),               \
      (__attribute__((address_space(3))) void*)(lptr), 16, 0, 0)

// fp4 e2m1 encode (weights only; RNE; magnitudes 0,.5,1,1.5,2,3,4,6)
__device__ inline uint32_t f2fp4(float v) {
  uint32_t s = (__float_as_uint(v) >> 31) << 3;
  float a = fabsf(v);
  uint32_t m;
  if (a < 0.25f) m = 0;
  else if (a < 0.75f) m = 1;
  else if (a < 1.25f) m = 2;
  else if (a < 1.75f) m = 3;
  else if (a < 2.5f)  m = 4;
  else if (a < 3.5f)  m = 5;
  else if (a < 5.0f)  m = 6;
  else m = 7;
  return s | m;
}

// ---------------- workspace layout (bytes) ---------------------------------
static constexpr size_t OFF_LIN  = 0;                          // 16384 f32
static constexpr size_t OFF_PART = 65536;                      // 4096 f32
static constexpr size_t OFF_S    = 81920;                      // 1 f32
static constexpr size_t OFF_ACC  = 98304;                      // 16384 f32 (mlp dot)
static constexpr size_t OFF_EMB  = 262144;                     // B*512 fp8
static constexpr size_t OFF_H1   = OFF_EMB + 8388608ull;       // B*2048 fp8
static constexpr size_t OFF_H2   = OFF_H1 + 33554432ull;       // B*1024 fp8
static constexpr size_t OFF_W1T  = OFF_H2 + 16777216ull;       // 2048*512 fp4
static constexpr size_t OFF_W2T  = OFF_W1T + 524288ull;        // 1024*2048 fp4
static constexpr size_t OFF_W3T  = OFF_W2T + 1048576ull;       // 512*1024 fp4

// ---------------- Stage 1: fused prep (transposes + gather) ----------------
__global__ void prep(const float* __restrict__ W1, const float* __restrict__ W2,
                     const float* __restrict__ W3, uint8_t* __restrict__ W1T,
                     uint8_t* __restrict__ W2T, uint8_t* __restrict__ W3T,
                     const float* __restrict__ x, const float* __restrict__ fc,
                     const float* __restrict__ emb, uint8_t* __restrict__ ebf,
                     float* __restrict__ lin, float* __restrict__ partials) {
  __shared__ __align__(16) float smem[32 * 33];
  int blk = blockIdx.x;
  int tid = threadIdx.x;
  if (blk < 3584) {  // ---- transpose ----
    const float* W;
    uint8_t* WT;
    int K, N, bx, by;
    if (blk < 1024) {        // W1: K=512, N=2048
      W = W1; WT = W1T; K = 512; N = 2048; bx = blk & 63; by = blk >> 6;
    } else if (blk < 3072) { // W2: K=2048, N=1024
      int t = blk - 1024;
      W = W2; WT = W2T; K = 2048; N = 1024; bx = t & 31; by = t >> 5;
    } else {                 // W3: K=1024, N=512
      int t = blk - 3072;
      W = W3; WT = W3T; K = 1024; N = 512; bx = t & 15; by = t >> 4;
    }
    int tx = tid & 31, ty = tid >> 5;
    int n0 = bx * 32, k0 = by * 32;
#pragma unroll
    for (int i = ty; i < 32; i += 8)
      smem[i * 33 + tx] = W[(size_t)(k0 + i) * N + n0 + tx];
    __syncthreads();
    if (tx < 16) {
#pragma unroll
      for (int i = ty; i < 32; i += 8) {
        uint32_t lo = f2fp4(smem[(2 * tx) * 33 + i] * 128.f);
        uint32_t hi = f2fp4(smem[(2 * tx + 1) * 33 + i] * 128.f);
        WT[(size_t)(n0 + i) * (K >> 1) + (k0 >> 1) + tx] =
            (uint8_t)(lo | (hi << 4));
      }
    }
  } else {  // ---- gather ----
    int gb = blk - 3584;
    int wv = tid >> 6, lane = tid & 63;
    int b = gb * 4 + wv;
    int f = lane >> 4;
    int idx = (int)x[b * 4 + f];               // raw index (NO offset) for emb
    const float* row = emb + (size_t)idx * 128 + (lane & 15) * 8;
    float4 v0 = ((const float4*)row)[0];
    float4 v1 = ((const float4*)row)[1];
    float s = v0.x + v0.y + v0.z + v0.w + v1.x + v1.y + v1.z + v1.w;
    float q = v0.x * v0.x + v0.y * v0.y + v0.z * v0.z + v0.w * v0.w +
              v1.x * v1.x + v1.y * v1.y + v1.z * v1.z + v1.w * v1.w;

    int lo = 0, hi = 0;
    lo = __builtin_amdgcn_cvt_pk_fp8_f32(v0.x, v0.y, lo, false);
    lo = __builtin_amdgcn_cvt_pk_fp8_f32(v0.z, v0.w, lo, true);
    hi = __builtin_amdgcn_cvt_pk_fp8_f32(v1.x, v1.y, hi, false);
    hi = __builtin_amdgcn_cvt_pk_fp8_f32(v1.z, v1.w, hi, true);
    int2 pk = make_int2(lo, hi);
    *(int2*)(ebf + (size_t)b * 512 + lane * 8) = pk;   // 8 B/lane coalesced

    float lp = 0.f;
    if ((lane & 15) == 0) {                    // fc lookup USES offsets
      int off = (f == 1) ? 31360 : (f == 2) ? 38167 : (f == 3) ? 38185 : 0;
      lp = fc[idx + off];
    }
#pragma unroll
    for (int m = 32; m; m >>= 1) {
      s += __shfl_xor(s, m);
      q += __shfl_xor(q, m);
      lp += __shfl_xor(lp, m);
    }
    float* pt = smem;
    if (lane == 0) {
      lin[b] = lp;
      pt[wv] = s * s - q;                      // per-sample FM term
    }
    __syncthreads();
    if (tid == 0) partials[gb] = pt[0] + pt[1] + pt[2] + pt[3];
  }
}

// ---------------- Stage 2: reduce FM partials + zero mlp accumulator -------
__global__ void reduce_partials(const float* __restrict__ p,
                                float* __restrict__ S,
                                float* __restrict__ dotacc) {
  int tid = threadIdx.x;
  float v = 0.f;
  for (int i = tid; i < 4096; i += 256) v += p[i];
#pragma unroll
  for (int m = 32; m; m >>= 1) v += __shfl_xor(v, m);
  __shared__ float ps[4];
  if ((tid & 63) == 0) ps[tid >> 6] = v;
  __syncthreads();
  if (tid == 0) S[0] = ps[0] + ps[1] + ps[2] + ps[3];
  float4 z4 = make_float4(0.f, 0.f, 0.f, 0.f);
  for (int i = tid; i < 4096; i += 256) ((float4*)dotacc)[i] = z4;
}

// ---------------- Stage 3: mixed GEMM, C = relu(A*B + bias) ----------------
// A fp8 (stride K B), BT fp4 (stride K/2 B), C fp8 (stride N B).
// 128x128 tile, BK=256 elems. A LDS rows 256 B (16-chunk XOR swizzle),
// B LDS rows 128 B (8-chunk XOR swizzle) — both measured conflict-free.
// global_load_lds width=16 staging (R7-verified). MFMA 16x16x128 f8f6f4:
// cbsz=0 (fp8 A), blgp=4 (fp4 B), scale_a=1, scale_b=2^-7 (undoes W
// pre-scale). 1-D grid, XCD swizzle: same-A-strip blocks share bid%8.
__global__ __launch_bounds__(256) void gemm_mx_relu(
    const uint8_t* __restrict__ A, const uint8_t* __restrict__ BT,
    const float* __restrict__ bias, uint8_t* __restrict__ C, int K, int N,
    int GX) {
  __shared__ __align__(16) uint8_t As[128][256];   // 32 KB
  __shared__ __align__(16) uint8_t Bs[128][128];   // 16 KB
  int bid = blockIdx.x;
  int by = (bid & 7) + ((bid >> 3) / GX) * 8;
  int bx = (bid >> 3) & (GX - 1);
  int tid = threadIdx.x;
  int wv = tid >> 6, lane = tid & 63;
  int m0 = by * 128, n0 = bx * 128;
  int mw = (wv >> 1) * 64, nw = (wv & 1) * 64;
  int ml = lane & 15, kg = lane >> 4;
  int Kb2 = K >> 1;
  int arow = lane >> 4;                        // A: 4-row staging groups
  int brow = lane >> 3;                        // B: 8-row staging groups
  int bcol = ((lane & 7) ^ brow) * 16;

  f32x4 acc[4][4];
#pragma unroll
  for (int i = 0; i < 4; ++i)
#pragma unroll
    for (int j = 0; j < 4; ++j) acc[i][j] = (f32x4){0.f, 0.f, 0.f, 0.f};

  for (int kt = 0; kt < K; kt += 256) {
#pragma unroll
    for (int r = 0; r < 8; ++r) {              // A: 32 groups of 4 rows
      int g = r * 4 + wv;
      int trow = 4 * g + arow;
      int acol = ((lane & 15) ^ (trow & 15)) * 16;
      const uint8_t* ga = A + (size_t)(m0 + trow) * K + kt + acol;
      GLOAD16(ga, &As[4 * g][0]);
    }
#pragma unroll
    for (int r = 0; r < 4; ++r) {              // B: 16 groups of 8 rows
      int g = r * 4 + wv;
      const uint8_t* gb =
          BT + (size_t)(n0 + 8 * g + brow) * Kb2 + (kt >> 1) + bcol;
      GLOAD16(gb, &Bs[8 * g][0]);
    }
    __syncthreads();

    i32x4 z = (i32x4){0, 0, 0, 0};
#pragma unroll
    for (int j = 0; j < 2; ++j) {              // two 128-elem k-halves
      int c0 = 8 * j + 2 * kg;
      int pa0 = (c0 ^ ml) * 16;
      int pa1 = ((c0 + 1) ^ ml) * 16;
      int pb = ((4 * j + kg) ^ (ml & 7)) * 16;
      i32x8 af[4], bfr[4];
#pragma unroll
      for (int t = 0; t < 4; ++t) {
        int ra = mw + t * 16 + ml;
        i32x4 a0 = *(const i32x4*)&As[ra][pa0];
        i32x4 a1 = *(const i32x4*)&As[ra][pa1];
        af[t] = __builtin_shufflevector(a0, a1, 0, 1, 2, 3, 4, 5, 6, 7);
        i32x4 vb = *(const i32x4*)&Bs[nw + t * 16 + ml][pb];
        bfr[t] = __builtin_shufflevector(vb, z, 0, 1, 2, 3, 4, 5, 6, 7);
      }
#pragma unroll
      for (int mt = 0; mt < 4; ++mt)
#pragma unroll
        for (int nt = 0; nt < 4; ++nt)
          acc[mt][nt] = __builtin_amdgcn_mfma_scale_f32_16x16x128_f8f6f4(
              af[mt], bfr[nt], acc[mt][nt],
              /*cbsz=fp8*/ 0, /*blgp=fp4*/ 4,
              0, 0x7F7F7F7F, 0, 0x78787878);
    }
    __syncthreads();
  }

  // Epilogue: C/D layout col=lane&15, row=(lane>>4)*4+reg.
  int rbase = kg * 4;
#pragma unroll
  for (int nt = 0; nt < 4; ++nt) {
    int col = n0 + nw + nt * 16 + ml;
    float bv = bias[col];
#pragma unroll
    for (int mt = 0; mt < 4; ++mt) {
      int row = m0 + mw + mt * 16 + rbase;
      float v0 = acc[mt][nt][0] + bv, v1 = acc[mt][nt][1] + bv;
      float v2 = acc[mt][nt][2] + bv, v3 = acc[mt][nt][3] + bv;
      v0 = v0 > 0.f ? v0 : 0.f;
      v1 = v1 > 0.f ? v1 : 0.f;
      v2 = v2 > 0.f ? v2 : 0.f;
      v3 = v3 > 0.f ? v3 : 0.f;
      int w01 = __builtin_amdgcn_cvt_pk_fp8_f32(v0, v1, 0, false);
      int w23 = __builtin_amdgcn_cvt_pk_fp8_f32(v2, v3, 0, false);
      C[(size_t)(row + 0) * N + col] = (uint8_t)(w01 & 0xFF);
      C[(size_t)(row + 1) * N + col] = (uint8_t)((w01 >> 8) & 0xFF);
      C[(size_t)(row + 2) * N + col] = (uint8_t)(w23 & 0xFF);
      C[(size_t)(row + 3) * N + col] = (uint8_t)((w23 >> 8) & 0xFF);
    }
  }
}

// ---------------- Stage 4: GEMM3 + fused L4 partial dot --------------------
// Same GEMM body; epilogue computes per-row partial dot of relu(.)+b3 slice
// with W4 and atomicAdds into dotacc[row]. H3 is never materialized.
__global__ __launch_bounds__(256) void gemm_mx_dot(
    const uint8_t* __restrict__ A, const uint8_t* __restrict__ BT,
    const float* __restrict__ bias, const float* __restrict__ W4,
    float* __restrict__ dotacc, int K, int N, int GX) {
  __shared__ __align__(16) uint8_t As[128][256];
  __shared__ __align__(16) uint8_t Bs[128][128];
  int bid = blockIdx.x;
  int by = (bid & 7) + ((bid >> 3) / GX) * 8;
  int bx = (bid >> 3) & (GX - 1);
  int tid = threadIdx.x;
  int wv = tid >> 6, lane = tid & 63;
  int m0 = by * 128, n0 = bx * 128;
  int mw = (wv >> 1) * 64, nw = (wv & 1) * 64;
  int ml = lane & 15, kg = lane >> 4;
  int Kb2 = K >> 1;
  int arow = lane >> 4;
  int brow = lane >> 3;
  int bcol = ((lane & 7) ^ brow) * 16;

  f32x4 acc[4][4];
#pragma unroll
  for (int i = 0; i < 4; ++i)
#pragma unroll
    for (int j = 0; j < 4; ++j) acc[i][j] = (f32x4){0.f, 0.f, 0.f, 0.f};

  for (int kt = 0; kt < K; kt += 256) {
#pragma unroll
    for (int r = 0; r < 8; ++r) {
      int g = r * 4 + wv;
      int trow = 4 * g + arow;
      int acol = ((lane & 15) ^ (trow & 15)) * 16;
      const uint8_t* ga = A + (size_t)(m0 + trow) * K + kt + acol;
      GLOAD16(ga, &As[4 * g][0]);
    }
#pragma unroll
    for (int r = 0; r < 4; ++r) {
      int g = r * 4 + wv;
      const uint8_t* gb =
          BT + (size_t)(n0 + 8 * g + brow) * Kb2 + (kt >> 1) + bcol;
      GLOAD16(gb, &Bs[8 * g][0]);
    }
    __syncthreads();

    i32x4 z = (i32x4){0, 0, 0, 0};
#pragma unroll
    for (int j = 0; j < 2; ++j) {
      int c0 = 8 * j + 2 * kg;
      int pa0 = (c0 ^ ml) * 16;
      int pa1 = ((c0 + 1) ^ ml) * 16;
      int pb = ((4 * j + kg) ^ (ml & 7)) * 16;
      i32x8 af[4], bfr[4];
#pragma unroll
      for (int t = 0; t < 4; ++t) {
        int ra = mw + t * 16 + ml;
        i32x4 a0 = *(const i32x4*)&As[ra][pa0];
        i32x4 a1 = *(const i32x4*)&As[ra][pa1];
        af[t] = __builtin_shufflevector(a0, a1, 0, 1, 2, 3, 4, 5, 6, 7);
        i32x4 vb = *(const i32x4*)&Bs[nw + t * 16 + ml][pb];
        bfr[t] = __builtin_shufflevector(vb, z, 0, 1, 2, 3, 4, 5, 6, 7);
      }
#pragma unroll
      for (int mt = 0; mt < 4; ++mt)
#pragma unroll
        for (int nt = 0; nt < 4; ++nt)
          acc[mt][nt] = __builtin_amdgcn_mfma_scale_f32_16x16x128_f8f6f4(
              af[mt], bfr[nt], acc[mt][nt],
              0, 4, 0, 0x7F7F7F7F, 0, 0x78787878);
    }
    __syncthreads();
  }

  // Fused epilogue: h = relu(acc + b3[col]); p[row] += h * W4[col];
  // reduce p over the 16 lanes sharing rows (shfl within 16-lane group),
  // lane ml==0 atomicAdds 16 rows. 2 n-waves -> 2 atomics/row/block.
  float bv[4], w4v[4];
#pragma unroll
  for (int nt = 0; nt < 4; ++nt) {
    int col = n0 + nw + nt * 16 + ml;
    bv[nt] = bias[col];
    w4v[nt] = W4[col];
  }
  int rbase = kg * 4;
#pragma unroll
  for (int mt = 0; mt < 4; ++mt) {
#pragma unroll
    for (int r = 0; r < 4; ++r) {
      float p = 0.f;
#pragma unroll
      for (int nt = 0; nt < 4; ++nt) {
        float v = acc[mt][nt][r] + bv[nt];
        v = v > 0.f ? v : 0.f;
        p += v * w4v[nt];
      }
#pragma unroll
      for (int m = 1; m < 16; m <<= 1) p += __shfl_xor(p, m);
      if (ml == 0)
        atomicAdd(&dotacc[m0 + mw + mt * 16 + rbase + r], p);
    }
  }
}

// ---------------- Stage 5: final sigmoid -----------------------------------
__global__ void final_out(const float* __restrict__ dotacc,
                          const float* __restrict__ lin,
                          const float* __restrict__ S,
                          const float* __restrict__ bias,
                          const float* __restrict__ b4,
                          float* __restrict__ out) {
  int i = blockIdx.x * 256 + threadIdx.x;
  float z = dotacc[i] + b4[0] + bias[0] + lin[i] + 0.5f * S[0];
  out[i] = 1.f / (1.f + expf(-z));
}

// ---------------------------------------------------------------------------
extern "C" void kernel_launch(void* const* d_in, const int* in_sizes, int n_in,
                              void* d_out, int out_size, void* d_ws,
                              size_t ws_size, hipStream_t stream) {
  const float* x    = (const float*)d_in[0];
  const float* bias = (const float*)d_in[1];
  const float* fc   = (const float*)d_in[2];
  const float* emb  = (const float*)d_in[3];
  const float* W1   = (const float*)d_in[4];
  const float* b1   = (const float*)d_in[5];
  const float* W2   = (const float*)d_in[6];
  const float* b2   = (const float*)d_in[7];
  const float* W3   = (const float*)d_in[8];
  const float* b3   = (const float*)d_in[9];
  const float* W4   = (const float*)d_in[10];
  const float* b4   = (const float*)d_in[11];
  float* out = (float*)d_out;

  char* ws = (char*)d_ws;
  float* lin    = (float*)(ws + OFF_LIN);
  float* part   = (float*)(ws + OFF_PART);
  float* Sp     = (float*)(ws + OFF_S);
  float* dacc   = (float*)(ws + OFF_ACC);
  uint8_t* EMBb = (uint8_t*)(ws + OFF_EMB);
  uint8_t* H1   = (uint8_t*)(ws + OFF_H1);
  uint8_t* H2   = (uint8_t*)(ws + OFF_H2);
  uint8_t* W1T  = (uint8_t*)(ws + OFF_W1T);
  uint8_t* W2T  = (uint8_t*)(ws + OFF_W2T);
  uint8_t* W3T  = (uint8_t*)(ws + OFF_W3T);

  prep<<<7680, 256, 0, stream>>>(W1, W2, W3, W1T, W2T, W3T, x, fc, emb, EMBb,
                                 lin, part);
  reduce_partials<<<1, 256, 0, stream>>>(part, Sp, dacc);

  gemm_mx_relu<<<2048, 256, 0, stream>>>(EMBb, W1T, b1, H1, 512, 2048, 16);
  gemm_mx_relu<<<1024, 256, 0, stream>>>(H1, W2T, b2, H2, 2048, 1024, 8);
  gemm_mx_dot<<<512, 256, 0, stream>>>(H2, W3T, b3, W4, dacc, 1024, 512, 4);

  final_out<<<64, 256, 0, stream>>>(dacc, lin, Sp, bias, b4, out);
}